// Round 5
// baseline (684.644 us; speedup 1.0000x reference)
//
#include <hip/hip_runtime.h>

typedef __bf16 bf16;
typedef __bf16 bf16x8 __attribute__((ext_vector_type(8)));
typedef __bf16 bf16x4 __attribute__((ext_vector_type(4)));
typedef float  f32x4  __attribute__((ext_vector_type(4)));

// ---------------------------------------------------------------------------
// f32 -> bf16 convert, 4-wide
// ---------------------------------------------------------------------------
__global__ void f2b_kernel(const float* __restrict__ src, bf16* __restrict__ dst, int n4) {
    int i = blockIdx.x * 256 + threadIdx.x;
    if (i >= n4) return;
    float4 v = ((const float4*)src)[i];
    bf16x4 o = { (bf16)v.x, (bf16)v.y, (bf16)v.z, (bf16)v.w };
    ((bf16x4*)dst)[i] = o;
}

// ---------------------------------------------------------------------------
// Swizzle fp32 W (taps, cin, cout) into bf16 MFMA-B-fragment order:
//   Wf[tap][s][nt][lane][j] = W[tap][s*32 + (lane>>4)*8 + j][nt*16 + (lane&15)]
// ---------------------------------------------------------------------------
__global__ void swz_kernel(const float* __restrict__ W, bf16* __restrict__ Wf,
                           int cin, int cout, int total) {
    int e = blockIdx.x * 256 + threadIdx.x;
    if (e >= total) return;
    int per_tap = cin * cout;
    int tap = e / per_tap;
    int t2  = e - tap * per_tap;
    int ntc = cout >> 4;
    int s   = t2 / (ntc * 512);
    int r3  = t2 - s * (ntc * 512);
    int nt  = r3 >> 9;
    int L   = (r3 & 511) >> 3;
    int j   = r3 & 7;
    int k   = s * 32 + (L >> 4) * 8 + j;
    int col = nt * 16 + (L & 15);
    Wf[e] = (bf16)W[((size_t)tap * cin + k) * cout + col];
}

// ---------------------------------------------------------------------------
// Fused chain: h1 = relu(bn(sconv(X,W1))); h2 = relu(bn(h1@W2));
//              optional h3 = relu(bn(h2@W3)).
// Stage 1 (sparse conv): NO LDS, NO barriers in the tap loop. Each wave
// gathers its MFMA A-fragments directly global->VGPR (lane m16 = row,
// quad = contiguous 64B k-chunk of that row; invalid neighbors exec-masked
// to zero). B-fragments global->VGPR (L2-hot). Register double-buffered
// (1-tap lookahead). Waves free-run => latency hidden by 16+ waves/CU.
// Stage 2/3 (dense): h-tile handoff through LDS, one barrier each side.
// ---------------------------------------------------------------------------
template<int CIN, int C1, int TAPS, int C2, int C3, int ROWS>
__global__ __launch_bounds__(256) void layer_kernel(
    const bf16* __restrict__ X,
    const bf16* __restrict__ W1,     // swizzled (TAPS, CIN, C1)
    const bf16* __restrict__ W2,     // swizzled (C1, C2)
    const bf16* __restrict__ W3,     // swizzled (C2, C3) or null
    const int*  __restrict__ nbr,    // (TAPS, n)
    const float* __restrict__ sc1, const float* __restrict__ sh1,
    const float* __restrict__ sc2, const float* __restrict__ sh2,
    const float* __restrict__ sc3, const float* __restrict__ sh3,
    bf16* __restrict__ Y, float* __restrict__ Yf,
    int ystride, int yoff, int n, int nblocks)
{
    constexpr int KH  = CIN / 32;          // k-steps (KTILE=32)
    constexpr int NT1 = C1 / 16;
    constexpr int CG1 = (C1 == 128) ? 4 : 2;
    constexpr int WC1 = NT1 / CG1;
    constexpr int RG1 = 4 / CG1;
    constexpr int WR1 = ROWS / 16 / RG1;
    constexpr int TOTAL = KH * TAPS;
    constexpr int LS1 = C1 + 8;
    constexpr int LS2 = C2 + 8;
    constexpr int TILE_E = (C3 > 0)
        ? (ROWS * LS1 > ROWS * LS2 ? ROWS * LS1 : ROWS * LS2)
        : ROWS * LS1;

    __shared__ int idxs[TAPS * ROWS];
    __shared__ __align__(16) bf16 tile[TILE_E];

    const int tid = threadIdx.x;

    // XCD-contiguous block swizzle (bijection, perf-only)
    const int bq = nblocks >> 3, br = nblocks & 7;
    const int bx = blockIdx.x & 7, bs = blockIdx.x >> 3;
    const int sb = bx * bq + (bx < br ? bx : br) + bs;
    const int base = sb * ROWS;

    const int lane = tid & 63;
    const int wv   = tid >> 6;
    const int m16  = lane & 15;
    const int quad = lane >> 4;
    const int wrow1 = wv % RG1;
    const int wcol1 = wv / RG1;
    const int r0 = wrow1 * WR1 * 16 + m16;       // lane's base row in tile

    for (int e = tid; e < TAPS * ROWS; e += 256)
        idxs[e] = nbr[(e / ROWS) * n + base + (e % ROWS)];
    __syncthreads();

    f32x4 acc1[WR1][WC1];
#pragma unroll
    for (int r = 0; r < WR1; ++r)
#pragma unroll
        for (int c = 0; c < WC1; ++c) acc1[r][c] = (f32x4){0.f, 0.f, 0.f, 0.f};

    const bf16 z0 = (bf16)0.f;
    const int boff = wcol1 * WC1 * 512 + lane * 8;
    const int koff = quad * 8;

    bf16x8 Acur[WR1], Bcur[WC1], Anxt[WR1], Bnxt[WC1];

    auto load_frags = [&](int it, bf16x8 (&A)[WR1], bf16x8 (&B)[WC1]) {
        int t = it % TAPS, kh = it / TAPS;
        const bf16* wt = W1 + ((size_t)t * KH + kh) * (NT1 * 512) + boff;
#pragma unroll
        for (int c = 0; c < WC1; ++c)
            B[c] = *(const bf16x8*)(wt + c * 512);
#pragma unroll
        for (int r = 0; r < WR1; ++r) {
            int idx = idxs[t * ROWS + r0 + r * 16];
            bf16x8 a = {z0, z0, z0, z0, z0, z0, z0, z0};
            if (idx >= 0)
                a = *(const bf16x8*)(X + (size_t)idx * CIN + kh * 32 + koff);
            A[r] = a;
        }
    };
    auto do_mfma = [&](bf16x8 (&A)[WR1], bf16x8 (&B)[WC1]) {
#pragma unroll
        for (int r = 0; r < WR1; ++r)
#pragma unroll
            for (int c = 0; c < WC1; ++c)
                acc1[r][c] = __builtin_amdgcn_mfma_f32_16x16x32_bf16(A[r], B[c], acc1[r][c], 0, 0, 0);
    };

    load_frags(0, Acur, Bcur);
    int it = 0;
    while (true) {
        if (it + 1 < TOTAL) load_frags(it + 1, Anxt, Bnxt);
        do_mfma(Acur, Bcur);
        ++it; if (it == TOTAL) break;
        if (it + 1 < TOTAL) load_frags(it + 1, Acur, Bcur);
        do_mfma(Anxt, Bnxt);
        ++it; if (it == TOTAL) break;
    }

    // ---- stage-1 epilogue -> LDS tile ----
#pragma unroll
    for (int c = 0; c < WC1; ++c) {
        int col = (wcol1 * WC1 + c) * 16 + m16;
        float s1 = sc1[col], h1 = sh1[col];
#pragma unroll
        for (int r = 0; r < WR1; ++r) {
            int row0 = (wrow1 * WR1 + r) * 16 + quad * 4;
#pragma unroll
            for (int i = 0; i < 4; ++i) {
                float v = acc1[r][c][i] * s1 + h1;
                v = v > 0.f ? v : 0.f;
                tile[(row0 + i) * LS1 + col] = (bf16)v;
            }
        }
    }
    __syncthreads();

    // ---- stage 2: dense GEMM K=C1 ----
    constexpr int NT2 = C2 / 16;
    constexpr int CG2 = (C2 == 128) ? 4 : 2;
    constexpr int WC2 = NT2 / CG2;
    constexpr int RG2 = 4 / CG2;
    constexpr int WR2 = ROWS / 16 / RG2;
    constexpr int KS2 = C1 / 32;
    const int wrow2 = wv % RG2, wcol2 = wv / RG2;

    f32x4 acc2[WR2][WC2];
#pragma unroll
    for (int r = 0; r < WR2; ++r)
#pragma unroll
        for (int c = 0; c < WC2; ++c) acc2[r][c] = (f32x4){0.f, 0.f, 0.f, 0.f};

#pragma unroll
    for (int s = 0; s < KS2; ++s) {
        bf16x8 a[WR2], bw[WC2];
#pragma unroll
        for (int r = 0; r < WR2; ++r)
            a[r] = *(const bf16x8*)(&tile[((wrow2 * WR2 + r) * 16 + m16) * LS1 + s * 32 + quad * 8]);
#pragma unroll
        for (int c = 0; c < WC2; ++c)
            bw[c] = *(const bf16x8*)(W2 + ((s * NT2 + wcol2 * WC2 + c) * 512 + lane * 8));
#pragma unroll
        for (int r = 0; r < WR2; ++r)
#pragma unroll
            for (int c = 0; c < WC2; ++c)
                acc2[r][c] = __builtin_amdgcn_mfma_f32_16x16x32_bf16(a[r], bw[c], acc2[r][c], 0, 0, 0);
    }

    if constexpr (C3 == 0) {
#pragma unroll
        for (int c = 0; c < WC2; ++c) {
            int col = (wcol2 * WC2 + c) * 16 + m16;
            float s2 = sc2[col], h2 = sh2[col];
#pragma unroll
            for (int r = 0; r < WR2; ++r) {
                int row0 = base + (wrow2 * WR2 + r) * 16 + quad * 4;
#pragma unroll
                for (int i = 0; i < 4; ++i) {
                    float v = acc2[r][c][i] * s2 + h2;
                    v = v > 0.f ? v : 0.f;
                    size_t off = (size_t)(row0 + i) * ystride + yoff + col;
                    if (Yf) Yf[off] = v;
                    else    Y[off] = (bf16)v;
                }
            }
        }
    } else {
        __syncthreads();                       // tile reads done
#pragma unroll
        for (int c = 0; c < WC2; ++c) {
            int col = (wcol2 * WC2 + c) * 16 + m16;
            float s2 = sc2[col], h2 = sh2[col];
#pragma unroll
            for (int r = 0; r < WR2; ++r) {
                int row0 = (wrow2 * WR2 + r) * 16 + quad * 4;
#pragma unroll
                for (int i = 0; i < 4; ++i) {
                    float v = acc2[r][c][i] * s2 + h2;
                    v = v > 0.f ? v : 0.f;
                    tile[(row0 + i) * LS2 + col] = (bf16)v;
                }
            }
        }
        __syncthreads();

        constexpr int C3v = (C3 > 0) ? C3 : 16;
        constexpr int NT3 = C3v / 16;
        constexpr int CG3 = (C3v == 128) ? 4 : 2;
        constexpr int WC3 = NT3 / CG3;
        constexpr int RG3 = 4 / CG3;
        constexpr int WR3 = ROWS / 16 / RG3;
        constexpr int KS3 = C2 / 32;
        const int wrow3 = wv % RG3, wcol3 = wv / RG3;

        f32x4 acc3[WR3][WC3];
#pragma unroll
        for (int r = 0; r < WR3; ++r)
#pragma unroll
            for (int c = 0; c < WC3; ++c) acc3[r][c] = (f32x4){0.f, 0.f, 0.f, 0.f};

#pragma unroll
        for (int s = 0; s < KS3; ++s) {
            bf16x8 a[WR3], bw[WC3];
#pragma unroll
            for (int r = 0; r < WR3; ++r)
                a[r] = *(const bf16x8*)(&tile[((wrow3 * WR3 + r) * 16 + m16) * LS2 + s * 32 + quad * 8]);
#pragma unroll
            for (int c = 0; c < WC3; ++c)
                bw[c] = *(const bf16x8*)(W3 + ((s * NT3 + wcol3 * WC3 + c) * 512 + lane * 8));
#pragma unroll
            for (int r = 0; r < WR3; ++r)
#pragma unroll
                for (int c = 0; c < WC3; ++c)
                    acc3[r][c] = __builtin_amdgcn_mfma_f32_16x16x32_bf16(a[r], bw[c], acc3[r][c], 0, 0, 0);
        }

#pragma unroll
        for (int c = 0; c < WC3; ++c) {
            int col = (wcol3 * WC3 + c) * 16 + m16;
            float s3 = sc3[col], h3 = sh3[col];
#pragma unroll
            for (int r = 0; r < WR3; ++r) {
                int row0 = base + (wrow3 * WR3 + r) * 16 + quad * 4;
#pragma unroll
                for (int i = 0; i < 4; ++i) {
                    float v = acc3[r][c][i] * s3 + h3;
                    v = v > 0.f ? v : 0.f;
                    size_t off = (size_t)(row0 + i) * ystride + yoff + col;
                    if (Yf) Yf[off] = v;
                    else    Y[off] = (bf16)v;
                }
            }
        }
    }
}

// ---------------------------------------------------------------------------
// z[:, 64:96] = sanitize(y2[align_idx])
// ---------------------------------------------------------------------------
__global__ void concat_kernel(const bf16* __restrict__ y2, const int* __restrict__ align,
                              bf16* __restrict__ z, int n) {
    int e = blockIdx.x * 256 + threadIdx.x;
    if (e >= n * 32) return;
    int i = e >> 5, c = e & 31;
    int a = align[i];
    float v = (float)y2[(size_t)a * 32 + c];
    unsigned u = __builtin_bit_cast(unsigned, v);
    if ((u & 0x7f800000u) == 0x7f800000u) v = 0.f;
    z[(size_t)i * 96 + 64 + c] = (bf16)v;
}

// ---------------------------------------------------------------------------
extern "C" void kernel_launch(void* const* d_in, const int* in_sizes, int n_in,
                              void* d_out, int out_size, void* d_ws, size_t ws_size,
                              hipStream_t stream) {
    const float* feat3d = (const float*)d_in[0];
    const float* feat2d = (const float*)d_in[1];
    const float* Wsrc[11];
    for (int i = 0; i < 11; ++i) Wsrc[i] = (const float*)d_in[2 + i];
    const float* bn[22];
    for (int i = 0; i < 22; ++i) bn[i] = (const float*)d_in[13 + i];
    const int* nbr   = (const int*)d_in[35];
    const int* align = (const int*)d_in[36];
    float* out = (float*)d_out;

    const int n = in_sizes[0] / 96;   // 80000 (divisible by 128)

    char* ws = (char*)d_ws;
    size_t off = 0;
    auto alloc = [&](size_t bytes) -> void* {
        void* p = ws + off;
        off = (off + bytes + 255) & ~(size_t)255;
        return p;
    };
    bf16* F3 = (bf16*)alloc((size_t)n * 96 * 2);
    bf16* F2 = (bf16*)alloc((size_t)n * 256 * 2);
    static const int wt_taps[11] = {27, 1, 27, 1, 27, 1, 27, 1, 27, 1, 1};
    static const int wt_cin[11]  = {96, 64, 64, 64, 256, 64, 64, 32, 96, 128, 128};
    static const int wt_cout[11] = {64, 64, 64, 64, 64, 64, 32, 32, 128, 128, 128};
    bf16* Wf[11];
    for (int i = 0; i < 11; ++i)
        Wf[i] = (bf16*)alloc((size_t)wt_taps[i] * wt_cin[i] * wt_cout[i] * 2);
    bf16* tA = (bf16*)alloc((size_t)n * 64 * 2);
    bf16* tB = (bf16*)alloc((size_t)n * 64 * 2);
    bf16* y2 = (bf16*)alloc((size_t)n * 32 * 2);
    bf16* z  = (bf16*)alloc((size_t)n * 96 * 2);

    f2b_kernel<<<(n * 96 / 4 + 255) / 256, 256, 0, stream>>>(feat3d, F3, n * 96 / 4);
    f2b_kernel<<<(n * 256 / 4 + 255) / 256, 256, 0, stream>>>(feat2d, F2, n * 256 / 4);
    for (int i = 0; i < 11; ++i) {
        int total = wt_taps[i] * wt_cin[i] * wt_cout[i];
        swz_kernel<<<(total + 255) / 256, 256, 0, stream>>>(Wsrc[i], Wf[i], wt_cin[i], wt_cout[i], total);
    }

    const int GB128 = n / 128;   // 625
    const int GB64  = n / 64;    // 1250

    // ---- 3D branch: (a1+a2), (a3+a4) ----
    layer_kernel<96, 64, 27, 64, 0, 128><<<GB128, 256, 0, stream>>>(
        F3, Wf[0], Wf[1], nullptr, nbr,
        bn[0], bn[1], bn[2], bn[3], nullptr, nullptr,
        tB, nullptr, 64, 0, n, GB128);
    layer_kernel<64, 64, 27, 64, 0, 128><<<GB128, 256, 0, stream>>>(
        tB, Wf[2], Wf[3], nullptr, nbr,
        bn[4], bn[5], bn[6], bn[7], nullptr, nullptr,
        z, nullptr, 96, 0, n, GB128);              // x3 -> z[:,0:64]

    // ---- 2D branch: (b1+b2), (b3+b4) ----
    layer_kernel<256, 64, 27, 64, 0, 128><<<GB128, 256, 0, stream>>>(
        F2, Wf[4], Wf[5], nullptr, nbr,
        bn[8], bn[9], bn[10], bn[11], nullptr, nullptr,
        tA, nullptr, 64, 0, n, GB128);
    layer_kernel<64, 32, 27, 32, 0, 128><<<GB128, 256, 0, stream>>>(
        tA, Wf[6], Wf[7], nullptr, nbr,
        bn[12], bn[13], bn[14], bn[15], nullptr, nullptr,
        y2, nullptr, 32, 0, n, GB128);

    concat_kernel<<<(n * 32 + 255) / 256, 256, 0, stream>>>(y2, align, z, n);

    // ---- fusion: (c1+c2+c3) ----
    layer_kernel<96, 128, 27, 128, 128, 64><<<GB64, 256, 0, stream>>>(
        z, Wf[8], Wf[9], Wf[10], nbr,
        bn[16], bn[17], bn[18], bn[19], bn[20], bn[21],
        nullptr, out, 128, 0, n, GB64);
}